// Round 1
// baseline (176.854 us; speedup 1.0000x reference)
//
#include <hip/hip_runtime.h>

#define NM    4096
#define NPTS  131072
#define CAP   128

typedef _Float16 h8 __attribute__((ext_vector_type(8)));
typedef _Float16 h2 __attribute__((ext_vector_type(2)));
typedef float    f4 __attribute__((ext_vector_type(4)));
typedef int      i4 __attribute__((ext_vector_type(4)));

#define MF(a, b, c) __builtin_amdgcn_mfma_f32_16x16x32_f16((a), (b), (c), 0, 0, 0)

#if __has_builtin(__builtin_amdgcn_global_load_lds)
#define USE_DMA 1
#else
#define USE_DMA 0
#endif

static __device__ inline h2 pk(float a, float b) {
    return __builtin_bit_cast(h2, __builtin_amdgcn_cvt_pkrtz(a, b));
}

static __device__ inline h8 pack8(float u0, float u1, float u2, float u3,
                                  float u4, float u5, float u6, float u7) {
    i4 t;
    t[0] = __builtin_bit_cast(int, pk(u0, u1));
    t[1] = __builtin_bit_cast(int, pk(u2, u3));
    t[2] = __builtin_bit_cast(int, pk(u4, u5));
    t[3] = __builtin_bit_cast(int, pk(u6, u7));
    return __builtin_bit_cast(h8, t);
}

// 8 guarded f16 from an fp32 row in LDS (reads unconditional + select).
static __device__ inline h8 lds_row8(const float* __restrict__ X, int base,
                                     int d0, int lim) {
    float u[8];
    #pragma unroll
    for (int jj = 0; jj < 8; jj++) {
        int d = d0 + jj;
        float raw = X[base + d];          // always in-bounds of X[6080]
        u[jj] = (d < lim) ? raw : 0.f;
    }
    return pack8(u[0], u[1], u[2], u[3], u[4], u[5], u[6], u[7]);
}

// aligned 8-float (32B) run in LDS -> h8 (two ds_read_b128)
static __device__ inline h8 lds_row8a(const float* __restrict__ X, int off) {
    f4 v0 = *(const f4*)(X + off);
    f4 v1 = *(const f4*)(X + off + 4);
    return pack8(v0[0], v0[1], v0[2], v0[3], v1[0], v1[1], v1[2], v1[3]);
}

// 8 guarded f16 from a global fp32 row (fallback staging path).
static __device__ inline h8 load_row8(const float* __restrict__ rb, int d0, int lim) {
    float u[8];
    #pragma unroll
    for (int jj = 0; jj < 8; jj++) {
        int d = d0 + jj;
        u[jj] = (d < lim) ? rb[d] : 0.f;
    }
    return pack8(u[0], u[1], u[2], u[3], u[4], u[5], u[6], u[7]);
}

// NeRF frequency-encoding dim d of (x,y,z); 0 for d >= lim.
static __device__ inline float encdim(int d, int lim, float x, float y, float z) {
    int tt = d - 3;
    int k  = tt / 6;
    int r  = tt - 6 * k;
    float p = x;
    p = (r == 1 || r == 4) ? y : p;
    p = (r == 2 || r == 5) ? z : p;
    float f   = __int_as_float((k + 127) << 23);   // 2^k
    float arg = p * f + ((r >= 3) ? 1.57079632679f : 0.f);  // cos = sin(+pi/2)
    float sv  = __sinf(arg);
    float raw = (d == 0) ? x : ((d == 1) ? y : z);
    float val = (d < 3) ? raw : sv;
    return (d < lim) ? val : 0.f;
}

// D-frag pair -> B-frag (verified in R8; see R8 notes for derivation).
static __device__ inline h8 makeB(f4 d0, f4 d1, int quad, int col) {
    int laneA = ((quad & 1) * 2) * 16 + col;
    int laneB = laneA + 16;
    float a0 = __shfl(d0[0], laneA), b0 = __shfl(d1[0], laneA);
    float a1 = __shfl(d0[1], laneA), b1 = __shfl(d1[1], laneA);
    float a2 = __shfl(d0[2], laneA), b2 = __shfl(d1[2], laneA);
    float a3 = __shfl(d0[3], laneA), b3 = __shfl(d1[3], laneA);
    float a4 = __shfl(d0[0], laneB), b4 = __shfl(d1[0], laneB);
    float a5 = __shfl(d0[1], laneB), b5 = __shfl(d1[1], laneB);
    float a6 = __shfl(d0[2], laneB), b6 = __shfl(d1[2], laneB);
    float a7 = __shfl(d0[3], laneB), b7 = __shfl(d1[3], laneB);
    bool hi = quad >= 2;
    return pack8(hi ? b0 : a0, hi ? b1 : a1, hi ? b2 : a2, hi ? b3 : a3,
                 hi ? b4 : a4, hi ? b5 : a5, hi ? b6 : a6, hi ? b7 : a7);
}

static __device__ inline f4 relu4(f4 a) {
    f4 r;
    r[0] = fmaxf(a[0], 0.f); r[1] = fmaxf(a[1], 0.f);
    r[2] = fmaxf(a[2], 0.f); r[3] = fmaxf(a[3], 0.f);
    return r;
}

#if USE_DMA
static __device__ inline void dma16(const float* g, const float* l) {
    __builtin_amdgcn_global_load_lds(
        (const __attribute__((address_space(1))) void*)g,
        (__attribute__((address_space(3))) void*)l, 16, 0, 0);
}
#endif

__global__ __launch_bounds__(256) void k_bucket(const float* __restrict__ pts,
                                                int* __restrict__ count,
                                                int* __restrict__ plist) {
    int n = blockIdx.x * 256 + threadIdx.x;
    if (n >= NPTS) return;
    float x = pts[3 * n + 0], y = pts[3 * n + 1], z = pts[3 * n + 2];
    int ix = (int)fminf(fmaxf(x * 16.f, 0.f), 15.f);
    int iy = (int)fminf(fmaxf(y * 16.f, 0.f), 15.f);
    int iz = (int)fminf(fmaxf(z * 16.f, 0.f), 15.f);
    int v = (ix << 8) | (iy << 4) | iz;
    int pos = atomicAdd(&count[v], 1);
    if (pos < CAP) plist[v * CAP + pos] = n;
}

// R9 restructure: 4 waves / block, single-stage staging.
//  - LDS 23.75 KB holds ALL weights at once:
//      w0 @0 (2016), w1 @2016 (1024), vw @3040 (1888), fw @4928 (1024),
//      sw @5952 (32), rw @5984 (96)  -> X[6080]
//  - ONE __syncthreads (vs 3): removes a full HBM drain from the critical path.
//  - Wave w owns point columns  w*16 + 64*i ; waves with no work exit right
//    after the barrier (avg unpack redundancy ~2x, not 4x).
//  - Resident waves/CU ~20 (VGPR-limited) vs ~5 before -> latency hiding.
__global__ __launch_bounds__(256) void k_mlp(
    const float* __restrict__ pts, const float* __restrict__ vds,
    const float* __restrict__ w0g, const float* __restrict__ b0g,
    const float* __restrict__ w1g, const float* __restrict__ b1g,
    const float* __restrict__ fwg, const float* __restrict__ fbg,
    const float* __restrict__ swg, const float* __restrict__ sbg,
    const float* __restrict__ vwg, const float* __restrict__ vbg,
    const float* __restrict__ rwg, const float* __restrict__ rbg,
    const int* __restrict__ count, const int* __restrict__ plist,
    float* __restrict__ out) {
    __shared__ __align__(16) float X[6080];   // 24320 B, all stages at once

    const int v = blockIdx.x;
    const int t = threadIdx.x;
    const int c = min(count[v], CAP);
    if (c == 0) return;

    const int wid  = t >> 6;
    const int lane = t & 63;
    const int col  = lane & 15;
    const int quad = lane >> 4;
    const int k8   = quad * 8;

    // ---- single-stage DMA: per-wave roles, all weights in flight at once ----
#if USE_DMA
    if (wid == 0) {
        const float* g = w0g + (size_t)v * 2016;
        #pragma unroll
        for (int k = 0; k < 7; k++) dma16(g + k * 256 + lane * 4, X + k * 256);
        if (lane < 56) dma16(g + 1792 + lane * 4, X + 1792);
    } else if (wid == 1) {
        const float* g = vwg + (size_t)v * 1888;
        #pragma unroll
        for (int k = 0; k < 7; k++) dma16(g + k * 256 + lane * 4, X + 3040 + k * 256);
        if (lane < 24) dma16(g + 1792 + lane * 4, X + 4832);
    } else if (wid == 2) {
        const float* g = w1g + (size_t)v * 1024;
        #pragma unroll
        for (int k = 0; k < 4; k++) dma16(g + k * 256 + lane * 4, X + 2016 + k * 256);
        if (lane < 8)  dma16(swg + (size_t)v * 32 + lane * 4, X + 5952);
        if (lane < 24) dma16(rwg + (size_t)v * 96 + lane * 4, X + 5984);
    } else {
        const float* g = fwg + (size_t)v * 1024;
        #pragma unroll
        for (int k = 0; k < 4; k++) dma16(g + k * 256 + lane * 4, X + 4928 + k * 256);
    }
#endif

    const bool hasWork = (wid * 16) < c;

    // ---- biases + first point prefetch (overlap the DMA drain) ----
    float pxc, pyc, pzc, dxc, dyc, dzc;
    int ncur = 0;
    f4 cB0[2], cB1[2], cFB[2], cVB[2];
    float rb0 = 0.f, rb1 = 0.f, rb2 = 0.f, sb = 0.f;
    if (hasWork) {
        int sl = min(wid * 16 + col, c - 1);
        ncur = plist[v * CAP + sl];
        pxc = pts[3 * ncur]; pyc = pts[3 * ncur + 1]; pzc = pts[3 * ncur + 2];
        int ray = ncur >> 7;
        dxc = vds[3 * ray]; dyc = vds[3 * ray + 1]; dzc = vds[3 * ray + 2];
        #pragma unroll
        for (int Ti = 0; Ti < 2; Ti++) {
            #pragma unroll
            for (int r = 0; r < 4; r++) {
                int row = Ti * 16 + quad * 4 + r;
                cB0[Ti][r] = b0g[v * 32 + row];
                cB1[Ti][r] = b1g[v * 32 + row];
                cFB[Ti][r] = fbg[v * 32 + row];
                cVB[Ti][r] = vbg[v * 32 + row];
            }
        }
        rb0 = rbg[v * 3 + 0]; rb1 = rbg[v * 3 + 1]; rb2 = rbg[v * 3 + 2];
        sb  = sbg[v];
    }

#if USE_DMA
    __syncthreads();   // ONE drain: all waves' DMA complete, then no more barriers
#endif
    if (!hasWork) return;

    // ---- unpack all fragments (active waves only) ----
    h8 aW0[2][2], aVW[2][2], aW1[2], aFW[2], aSG, aRGB;
#if USE_DMA
    #pragma unroll
    for (int Ti = 0; Ti < 2; Ti++) {
        int r0 = (Ti * 16 + col) * 63;
        aW0[Ti][0] = lds_row8(X, r0, k8, 63);
        aW0[Ti][1] = lds_row8(X, r0, 32 + k8, 63);
        aW1[Ti] = lds_row8a(X, 2016 + (Ti * 16 + col) * 32 + k8);
        int r1 = 3040 + (Ti * 16 + col) * 59;
        aVW[Ti][0] = lds_row8(X, r1, k8, 59);
        aVW[Ti][1] = lds_row8(X, r1, 32 + k8, 59);
        aFW[Ti] = lds_row8a(X, 4928 + (Ti * 16 + col) * 32 + k8);
    }
    aSG  = (col == 0) ? lds_row8a(X, 5952 + k8) : h8{};
    aRGB = (col < 3) ? lds_row8a(X, 5984 + col * 32 + k8) : h8{};
#else
    #pragma unroll
    for (int Ti = 0; Ti < 2; Ti++) {
        const float* rb = w0g + (size_t)v * 2016 + (Ti * 16 + col) * 63;
        aW0[Ti][0] = load_row8(rb, k8, 63);
        aW0[Ti][1] = load_row8(rb, 32 + k8, 63);
        rb = vwg + (size_t)v * 1888 + (Ti * 16 + col) * 59;
        aVW[Ti][0] = load_row8(rb, k8, 59);
        aVW[Ti][1] = load_row8(rb, 32 + k8, 59);
        aW1[Ti] = load_row8(w1g + (size_t)v * 1024 + (Ti * 16 + col) * 32, k8, 32);
        aFW[Ti] = load_row8(fwg + (size_t)v * 1024 + (Ti * 16 + col) * 32, k8, 32);
    }
    aSG  = (col == 0) ? load_row8(swg + (size_t)v * 32, k8, 32) : h8{};
    aRGB = (col < 3) ? load_row8(rwg + (size_t)v * 96 + col * 32, k8, 32) : h8{};
#endif

    const f4 z4 = {0.f, 0.f, 0.f, 0.f};

    for (int base = wid * 16; base < c; base += 64) {
        const bool active = (base + col) < c;
        const int n = ncur;
        const float px = pxc, py = pyc, pz = pzc;
        const float dx = dxc, dy = dyc, dz = dzc;

        if (base + 64 < c) {
            int sl = min(base + 64 + col, c - 1);
            ncur = plist[v * CAP + sl];
            pxc = pts[3 * ncur]; pyc = pts[3 * ncur + 1]; pzc = pts[3 * ncur + 2];
            int ray = ncur >> 7;
            dxc = vds[3 * ray]; dyc = vds[3 * ray + 1]; dzc = vds[3 * ray + 2];
        }

        h8 bE0 = pack8(encdim(k8 + 0, 63, px, py, pz), encdim(k8 + 1, 63, px, py, pz),
                       encdim(k8 + 2, 63, px, py, pz), encdim(k8 + 3, 63, px, py, pz),
                       encdim(k8 + 4, 63, px, py, pz), encdim(k8 + 5, 63, px, py, pz),
                       encdim(k8 + 6, 63, px, py, pz), encdim(k8 + 7, 63, px, py, pz));
        h8 bE1 = pack8(encdim(32 + k8 + 0, 63, px, py, pz), encdim(32 + k8 + 1, 63, px, py, pz),
                       encdim(32 + k8 + 2, 63, px, py, pz), encdim(32 + k8 + 3, 63, px, py, pz),
                       encdim(32 + k8 + 4, 63, px, py, pz), encdim(32 + k8 + 5, 63, px, py, pz),
                       encdim(32 + k8 + 6, 63, px, py, pz), encdim(32 + k8 + 7, 63, px, py, pz));

        // layer 0
        f4 d0 = MF(aW0[0][0], bE0, cB0[0]); d0 = MF(aW0[0][1], bE1, d0);
        f4 d1 = MF(aW0[1][0], bE0, cB0[1]); d1 = MF(aW0[1][1], bE1, d1);
        d0 = relu4(d0); d1 = relu4(d1);
        h8 bH = makeB(d0, d1, quad, col);

        // layer 1
        f4 e0 = MF(aW1[0], bH, cB1[0]);
        f4 e1 = MF(aW1[1], bH, cB1[1]);
        e0 = relu4(e0); e1 = relu4(e1);
        h8 bG = makeB(e0, e1, quad, col);

        // sigma
        f4 s = MF(aSG, bG, z4);

        // feature
        f4 f0 = MF(aFW[0], bG, cFB[0]);
        f4 f1 = MF(aFW[1], bG, cFB[1]);
        h8 bF = makeB(f0, f1, quad, col);

        // dir encoding
        h8 bD = pack8(encdim(k8 + 0, 27, dx, dy, dz), encdim(k8 + 1, 27, dx, dy, dz),
                      encdim(k8 + 2, 27, dx, dy, dz), encdim(k8 + 3, 27, dx, dy, dz),
                      encdim(k8 + 4, 27, dx, dy, dz), encdim(k8 + 5, 27, dx, dy, dz),
                      encdim(k8 + 6, 27, dx, dy, dz), encdim(k8 + 7, 27, dx, dy, dz));

        // view layer
        f4 v0 = MF(aVW[0][0], bF, cVB[0]); v0 = MF(aVW[0][1], bD, v0);
        f4 v1 = MF(aVW[1][0], bF, cVB[1]); v1 = MF(aVW[1][1], bD, v1);
        v0 = relu4(v0); v1 = relu4(v1);
        h8 bV = makeB(v0, v1, quad, col);

        // rgb
        f4 o = MF(aRGB, bV, z4);

        if (quad == 0 && active) {
            out[3 * n + 0] = o[0] + rb0;
            out[3 * n + 1] = o[1] + rb1;
            out[3 * n + 2] = o[2] + rb2;
            out[3 * NPTS + n] = s[0] + sb;
        }
    }
}

extern "C" void kernel_launch(void* const* d_in, const int* in_sizes, int n_in,
                              void* d_out, int out_size, void* d_ws, size_t ws_size,
                              hipStream_t stream) {
    const float* pts = (const float*)d_in[0];
    const float* vds = (const float*)d_in[1];
    const float* w0  = (const float*)d_in[2];
    const float* b0  = (const float*)d_in[3];
    const float* w1  = (const float*)d_in[4];
    const float* b1  = (const float*)d_in[5];
    const float* fw  = (const float*)d_in[6];
    const float* fb  = (const float*)d_in[7];
    const float* sw  = (const float*)d_in[8];
    const float* sb  = (const float*)d_in[9];
    const float* vw  = (const float*)d_in[10];
    const float* vb  = (const float*)d_in[11];
    const float* rw  = (const float*)d_in[12];
    const float* rb  = (const float*)d_in[13];
    float* out = (float*)d_out;

    int* count = (int*)d_ws;
    int* plist = (int*)((char*)d_ws + NM * sizeof(int));

    (void)hipMemsetAsync(count, 0, NM * sizeof(int), stream);
    k_bucket<<<NPTS / 256, 256, 0, stream>>>(pts, count, plist);
    k_mlp<<<NM, 256, 0, stream>>>(pts, vds, w0, b0, w1, b1, fw, fb, sw, sb,
                                  vw, vb, rw, rb, count, plist, out);
}